// Round 3
// baseline (4629.546 us; speedup 1.0000x reference)
//
#include <hip/hip_runtime.h>

typedef unsigned short u16;
typedef unsigned int uint;

using f32x4 = __attribute__((ext_vector_type(4))) float;
using bf16x8 = __attribute__((ext_vector_type(8))) __bf16;
using u16x4e = __attribute__((ext_vector_type(4))) u16;   // native vector for nontemporal builtin

static __device__ __forceinline__ bf16x8 as_bf16x8(uint4 u) {
    union { uint4 a; bf16x8 b; } c; c.a = u; return c.b;
}
static __device__ __forceinline__ float bf2f(u16 h) {
    union { uint u; float f; } c; c.u = ((uint)h) << 16; return c.f;
}
static __device__ __forceinline__ u16 f2bf(float f) {
    union { float f; uint u; } c; c.f = f;
    uint u = c.u;
    return (u16)((u + 0x7fffu + ((u >> 16) & 1u)) >> 16);
}
static __device__ __forceinline__ float fast_sigmoid(float x) {
    x = fminf(30.f, fmaxf(-30.f, x));
    return __builtin_amdgcn_rcpf(1.0f + __builtin_amdgcn_exp2f(x * -1.44269504f));
}
static __device__ __forceinline__ float fast_tanh(float x) {
    x = fminf(15.f, fmaxf(-15.f, x));
    return 1.0f - 2.0f * __builtin_amdgcn_rcpf(1.0f + __builtin_amdgcn_exp2f(x * 2.88539008f));
}
// Nontemporal embedding gather: keep the 2MB table from evicting L2-resident weights.
static __device__ __forceinline__ ushort4 ldnt4(const u16* p) {
    u16x4e v = __builtin_nontemporal_load((const u16x4e*)p);
    ushort4 r; r.x = v[0]; r.y = v[1]; r.z = v[2]; r.w = v[3];
    return r;
}

// dtype detector (fp32 vs bf16 buffers) — deterministic, graph-capture safe.
static __device__ __forceinline__ int detect_fp32(const uint* w, int nwords) {
    int hits = 0;
    for (int i = 0; i < nwords; ++i) { uint e = (w[i] >> 7) & 0xffu; hits += (e >= 0x80u); }
    return hits > (nwords >> 3);
}
static __device__ __forceinline__ u16 load_bf(const void* p, int i, int fp32) {
    return fp32 ? f2bf(((const float*)p)[i]) : ((const u16*)p)[i];
}

// Fragment-ordered weight pack:
//   wp[((w*KSTEPS + ks)*4 + nt)*512 + lane*8 + j]
//   n = w*64 + nt*16 + (lane&15) = 4*unit + gate;  k = ks*32 + (lane>>4)*8 + j
// -> every B-fragment load in the main loop is base + lane*16B (coalesced 1KB).
// grid: 16*KSTEPS blocks x 256 threads.
__global__ void pack_w(const void* wf, const void* wi, const void* wc, const void* wo,
                       const void* bbf, const void* bbi, const void* bbc, const void* bbo,
                       u16* __restrict__ wp, u16* __restrict__ bp, int K, int KSTEPS) {
    __shared__ int sfp;
    if (threadIdx.x == 0) sfp = detect_fp32((const uint*)wf, 256);
    __syncthreads();
    const int fp32 = sfp;
    int w = blockIdx.x / KSTEPS, ks = blockIdx.x % KSTEPS;
    int nt = threadIdx.x >> 6, lane = threadIdx.x & 63;
    int c16 = lane & 15, q = lane >> 4;
    int n = w * 64 + nt * 16 + c16;
    int u = n >> 2, g = n & 3;
    const void* W = (g == 0) ? wf : (g == 1) ? wi : (g == 2) ? wc : wo;
    union { u16 v[8]; uint4 u4; } tmp;
#pragma unroll
    for (int j = 0; j < 8; ++j) {
        int k = ks * 32 + q * 8 + j;
        tmp.v[j] = (k < K) ? load_bf(W, k * 256 + u, fp32) : (u16)0;
    }
    *(uint4*)(wp + ((w * KSTEPS + ks) * 4 + nt) * 512 + lane * 8) = tmp.u4;
    if (ks == 0 && threadIdx.x < 64) {
        int n2 = w * 64 + threadIdx.x;
        int g2 = n2 & 3;
        const void* B = (g2 == 0) ? bbf : (g2 == 1) ? bbi : (g2 == 2) ? bbc : bbo;
        bp[n2] = load_bf(B, n2 >> 2, fp32);
    }
}

// Pack embedding table + w_out/b_out to bf16 in workspace.
__global__ void pack_misc(const void* emb, const void* w_out, const void* b_out,
                          u16* __restrict__ embp, u16* __restrict__ wob,
                          u16* __restrict__ bob) {
    __shared__ int sfp;
    if (threadIdx.x == 0) sfp = detect_fp32((const uint*)emb, 256);
    __syncthreads();
    const int fp32 = sfp;
    int stride = gridDim.x * blockDim.x;
    for (int i = blockIdx.x * blockDim.x + threadIdx.x; i < 1000000; i += stride)
        embp[i] = load_bf(emb, i, fp32);
    if (blockIdx.x == 0) {
        __shared__ int sfp2;
        if (threadIdx.x == 0) sfp2 = detect_fp32((const uint*)w_out, 128);
        __syncthreads();
        if (threadIdx.x < 256) wob[threadIdx.x] = load_bf(w_out, threadIdx.x, sfp2);
        if (threadIdx.x == 0) bob[0] = load_bf(b_out, 0, sfp2);
    }
}

// K-loop, M=32: acc[m][nt] += HX[32,K] x W[K, 16 cols], weights in fragment order.
// Each 1KB B-fragment load now feeds TWO MFMAs (rows 0-15 and 16-31): 2x the
// arithmetic intensity per byte pulled through the CU<->L2 path.
template <int KSTEPS, int HXS>
static __device__ __forceinline__ void kloop2(const u16* __restrict__ wslab, const u16* hx,
                                              int lane, f32x4 acc[2][4]) {
    int c16 = lane & 15, q = lane >> 4;
    const u16* aptr = hx + c16 * HXS + q * 8;
    const u16* bptr = wslab + lane * 8;
    uint4 bb[2][4];
#pragma unroll
    for (int nt = 0; nt < 4; ++nt) bb[0][nt] = *(const uint4*)(bptr + nt * 512);
#pragma unroll
    for (int ks = 0; ks < KSTEPS; ++ks) {
        int cur = ks & 1;
        if (ks + 1 < KSTEPS) {
#pragma unroll
            for (int nt = 0; nt < 4; ++nt)
                bb[cur ^ 1][nt] = *(const uint4*)(bptr + ((ks + 1) * 4 + nt) * 512);
        }
        bf16x8 a0 = as_bf16x8(*(const uint4*)(aptr + ks * 32));
        bf16x8 a1 = as_bf16x8(*(const uint4*)(aptr + 16 * HXS + ks * 32));
#pragma unroll
        for (int nt = 0; nt < 4; ++nt) {
            bf16x8 b = as_bf16x8(bb[cur][nt]);
            acc[0][nt] = __builtin_amdgcn_mfma_f32_16x16x32_bf16(a0, b, acc[0][nt], 0, 0, 0);
            acc[1][nt] = __builtin_amdgcn_mfma_f32_16x16x32_bf16(a1, b, acc[1][nt], 0, 0, 0);
        }
    }
}

#define HX1S 392   // 356 K-cols + pad
#define HX2S 520   // 512 K-cols + 8 pad
#define SCRS 68    // 64 gate-cols + 4 pad
#define ROWS 32    // rows (batch elements) per block

__global__ void __launch_bounds__(1024, 1)
lstm_kernel(const int* __restrict__ tokens, const u16* __restrict__ embp,
            const u16* __restrict__ wp1, const u16* __restrict__ b1p,
            const u16* __restrict__ wp2, const u16* __restrict__ b2p,
            const u16* __restrict__ wob, const u16* __restrict__ bob,
            float* __restrict__ out) {
    __shared__ __align__(16) u16 hx1[ROWS * HX1S];        // 25088 B [r][ h1 | x | 0-pad ]
    __shared__ __align__(16) u16 hx2[ROWS * HX2S];        // 33280 B [r][ h2 | h1 ]
    __shared__ __align__(16) u16 scr[16 * ROWS * SCRS];   // 69632 B per-wave Z scratch
    // total 128,000 B LDS -> 1 block/CU

    const int tid = threadIdx.x;
    const int lane = tid & 63;
    const int w = tid >> 6;          // wave 0..15 -> gate-cols [64w, 64w+64)
    const int c16 = lane & 15;
    const int q = lane >> 4;
    const int row0 = blockIdx.x * ROWS;

    const int ul = lane & 15;        // unit-local for gates
    const int U = w * 16 + ul;       // global unit 0..255

    {
        uint* p1 = (uint*)hx1;
        for (int i = tid; i < ROWS * HX1S / 2; i += 1024) p1[i] = 0;
        uint* p2 = (uint*)hx2;
        for (int i = tid; i < ROWS * HX2S / 2; i += 1024) p2[i] = 0;
    }
    float c1s[8], c2s[8];
#pragma unroll
    for (int j = 0; j < 8; ++j) { c1s[j] = 0.f; c2s[j] = 0.f; }

    // gather x(t=0): 32 rows x 25 ushort4, all 1024 threads
    {
        int r = tid >> 5, s32 = tid & 31;
        if (s32 < 25) {
            int tok = tokens[(row0 + r) * 80 + 0];
            ushort4 v = ldnt4(embp + tok * 100 + s32 * 4);
            *(ushort4*)(hx1 + r * HX1S + 256 + s32 * 4) = v;
        }
    }
    ushort4 bw1 = *(const ushort4*)(b1p + U * 4);
    ushort4 bw2 = *(const ushort4*)(b2p + U * 4);
    const float b1f0 = bf2f(bw1.x), b1f1 = bf2f(bw1.y), b1f2 = bf2f(bw1.z), b1f3 = bf2f(bw1.w);
    const float b2f0 = bf2f(bw2.x), b2f1 = bf2f(bw2.y), b2f2 = bf2f(bw2.z), b2f3 = bf2f(bw2.w);

    __syncthreads();

    u16* sw = scr + w * ROWS * SCRS;
    const u16* w1slab = wp1 + w * (12 * 4 * 512);
    const u16* w2slab = wp2 + w * (16 * 4 * 512);

#pragma unroll 1
    for (int t = 0; t < 80; ++t) {
        // ---------- Layer 1 GEMM ----------
        f32x4 acc[2][4];
#pragma unroll
        for (int m = 0; m < 2; ++m)
#pragma unroll
            for (int nt = 0; nt < 4; ++nt) acc[m][nt] = (f32x4){0.f, 0.f, 0.f, 0.f};
        kloop2<12, HX1S>(w1slab, hx1, lane, acc);
#pragma unroll
        for (int m = 0; m < 2; ++m)
#pragma unroll
            for (int nt = 0; nt < 4; ++nt)
#pragma unroll
                for (int j = 0; j < 4; ++j)
                    sw[(m * 16 + q * 4 + j) * SCRS + nt * 16 + c16] = f2bf(acc[m][nt][j]);
        __syncthreads();  // B1

        // ---------- gates 1 (+ x(t+1) prefetch) ----------
        ushort4 xv;
        int xr = tid >> 5, xs = tid & 31;
        bool xact = (xs < 25) && (t < 79);
        if (xact) {
            int tok = tokens[(row0 + xr) * 80 + t + 1];
            xv = ldnt4(embp + tok * 100 + xs * 4);
        }
#pragma unroll
        for (int jj = 0; jj < 8; ++jj) {
            int r = q * 8 + jj;
            ushort4 zz = *(const ushort4*)(sw + r * SCRS + ul * 4);
            float gf = fast_sigmoid(bf2f(zz.x) + b1f0);
            float gi = fast_sigmoid(bf2f(zz.y) + b1f1);
            float gc = fast_tanh(bf2f(zz.z) + b1f2);
            float go = fast_sigmoid(bf2f(zz.w) + b1f3);
            float cn = gf * c1s[jj] + gi * gc;
            c1s[jj] = cn;
            u16 hb = f2bf(go * fast_tanh(cn));
            hx1[r * HX1S + U] = hb;
            hx2[r * HX2S + 256 + U] = hb;
        }
        if (xact) *(ushort4*)(hx1 + xr * HX1S + 256 + xs * 4) = xv;
        __syncthreads();  // B2

        // ---------- Layer 2 GEMM ----------
        f32x4 acc2[2][4];
#pragma unroll
        for (int m = 0; m < 2; ++m)
#pragma unroll
            for (int nt = 0; nt < 4; ++nt) acc2[m][nt] = (f32x4){0.f, 0.f, 0.f, 0.f};
        kloop2<16, HX2S>(w2slab, hx2, lane, acc2);
#pragma unroll
        for (int m = 0; m < 2; ++m)
#pragma unroll
            for (int nt = 0; nt < 4; ++nt)
#pragma unroll
                for (int j = 0; j < 4; ++j)
                    sw[(m * 16 + q * 4 + j) * SCRS + nt * 16 + c16] = f2bf(acc2[m][nt][j]);
        __syncthreads();  // B3

        // ---------- gates 2 ----------
#pragma unroll
        for (int jj = 0; jj < 8; ++jj) {
            int r = q * 8 + jj;
            ushort4 zz = *(const ushort4*)(sw + r * SCRS + ul * 4);
            float gf = fast_sigmoid(bf2f(zz.x) + b2f0);
            float gi = fast_sigmoid(bf2f(zz.y) + b2f1);
            float gc = fast_tanh(bf2f(zz.z) + b2f2);
            float go = fast_sigmoid(bf2f(zz.w) + b2f3);
            float cn = gf * c2s[jj] + gi * gc;
            c2s[jj] = cn;
            hx2[r * HX2S + U] = f2bf(go * fast_tanh(cn));
        }
        // scr is wave-private; hx hazards ordered by B1/B2 of next iteration.
    }
    __syncthreads();

    // ---------- output: sigmoid(h2 @ w_out + b_out), fp32 store ----------
    {
        int r = tid >> 5, s = tid & 31;
        uint4 hv = *(const uint4*)(hx2 + r * HX2S + s * 8);
        uint4 wv = *(const uint4*)(wob + s * 8);
        const u16* hp = (const u16*)&hv;
        const u16* wpp = (const u16*)&wv;
        float dot = 0.f;
#pragma unroll
        for (int i = 0; i < 8; ++i) dot += bf2f(hp[i]) * bf2f(wpp[i]);
        float* psum = (float*)scr;
        psum[r * 32 + s] = dot;
    }
    __syncthreads();
    if (tid < 32) {
        float* psum = (float*)scr;
        float ssum = 0.f;
        for (int i = 0; i < 32; ++i) ssum += psum[tid * 32 + i];
        out[row0 + tid] = fast_sigmoid(ssum + bf2f(bob[0]));
    }
}

extern "C" void kernel_launch(void* const* d_in, const int* in_sizes, int n_in,
                              void* d_out, int out_size, void* d_ws, size_t ws_size,
                              hipStream_t stream) {
    const int* tokens = (const int*)d_in[0];
    const void* emb = d_in[1];
    const void* wf1 = d_in[2];  const void* bf1_ = d_in[3];
    const void* wi1 = d_in[4];  const void* bi1_ = d_in[5];
    const void* wc1 = d_in[6];  const void* bc1_ = d_in[7];
    const void* wo1 = d_in[8];  const void* bo1_ = d_in[9];
    const void* wf2 = d_in[10]; const void* bf2_ = d_in[11];
    const void* wi2 = d_in[12]; const void* bi2_ = d_in[13];
    const void* wc2 = d_in[14]; const void* bc2_ = d_in[15];
    const void* wo2 = d_in[16]; const void* bo2_ = d_in[17];
    const void* w_out = d_in[18];
    const void* b_out = d_in[19];

    u16* wp1 = (u16*)d_ws;                 // 16*12*4*512 = 393216
    u16* wp2 = wp1 + 16 * 12 * 4 * 512;    // 16*16*4*512 = 524288
    u16* b1p = wp2 + 16 * 16 * 4 * 512;    // 1024
    u16* b2p = b1p + 1024;                 // 1024
    u16* wob = b2p + 1024;                 // 256
    u16* bob = wob + 256;                  // 8 (pad)
    u16* embp = bob + 8;                   // 1,000,000

    pack_w<<<dim3(16 * 12), dim3(256), 0, stream>>>(wf1, wi1, wc1, wo1, bf1_, bi1_, bc1_, bo1_,
                                                    wp1, b1p, 356, 12);
    pack_w<<<dim3(16 * 16), dim3(256), 0, stream>>>(wf2, wi2, wc2, wo2, bf2_, bi2_, bc2_, bo2_,
                                                    wp2, b2p, 512, 16);
    pack_misc<<<dim3(512), dim3(256), 0, stream>>>(emb, w_out, b_out, embp, wob, bob);
    lstm_kernel<<<dim3(32), dim3(1024), 0, stream>>>(tokens, embp, wp1, b1p, wp2, b2p,
                                                     wob, bob, (float*)d_out);
}

// Round 4
// 1748.652 us; speedup vs baseline: 2.6475x; 2.6475x over previous
//
#include <hip/hip_runtime.h>

typedef unsigned short u16;
typedef unsigned int uint;

using f32x4 = __attribute__((ext_vector_type(4))) float;
using bf16x8 = __attribute__((ext_vector_type(8))) __bf16;

static __device__ __forceinline__ bf16x8 as_bf16x8(uint4 u) {
    union { uint4 a; bf16x8 b; } c; c.a = u; return c.b;
}
static __device__ __forceinline__ float bf2f(u16 h) {
    union { uint u; float f; } c; c.u = ((uint)h) << 16; return c.f;
}
static __device__ __forceinline__ u16 f2bf(float f) {
    union { float f; uint u; } c; c.f = f;
    uint u = c.u;
    return (u16)((u + 0x7fffu + ((u >> 16) & 1u)) >> 16);
}
static __device__ __forceinline__ float fast_sigmoid(float x) {
    x = fminf(30.f, fmaxf(-30.f, x));
    return __builtin_amdgcn_rcpf(1.0f + __builtin_amdgcn_exp2f(x * -1.44269504f));
}
static __device__ __forceinline__ float fast_tanh(float x) {
    x = fminf(15.f, fmaxf(-15.f, x));
    return 1.0f - 2.0f * __builtin_amdgcn_rcpf(1.0f + __builtin_amdgcn_exp2f(x * 2.88539008f));
}

// dtype detector (fp32 vs bf16 buffers) — deterministic, graph-capture safe.
static __device__ __forceinline__ int detect_fp32(const uint* w, int nwords) {
    int hits = 0;
    for (int i = 0; i < nwords; ++i) { uint e = (w[i] >> 7) & 0xffu; hits += (e >= 0x80u); }
    return hits > (nwords >> 3);
}
static __device__ __forceinline__ u16 load_bf(const void* p, int i, int fp32) {
    return fp32 ? f2bf(((const float*)p)[i]) : ((const u16*)p)[i];
}

// Fragment-ordered weight pack (unchanged layout):
//   wp[((w*KSTEPS + ks)*4 + nt)*512 + lane*8 + j]
//   n = w*64 + nt*16 + (lane&15) = 4*unit + gate;  k = ks*32 + (lane>>4)*8 + j
// Block g of the persistent kernel consumes the contiguous slice w==g.
__global__ void pack_w(const void* wf, const void* wi, const void* wc, const void* wo,
                       const void* bbf, const void* bbi, const void* bbc, const void* bbo,
                       u16* __restrict__ wp, u16* __restrict__ bp, int K, int KSTEPS) {
    __shared__ int sfp;
    if (threadIdx.x == 0) sfp = detect_fp32((const uint*)wf, 256);
    __syncthreads();
    const int fp32 = sfp;
    int w = blockIdx.x / KSTEPS, ks = blockIdx.x % KSTEPS;
    int nt = threadIdx.x >> 6, lane = threadIdx.x & 63;
    int c16 = lane & 15, q = lane >> 4;
    int n = w * 64 + nt * 16 + c16;
    int u = n >> 2, g = n & 3;
    const void* W = (g == 0) ? wf : (g == 1) ? wi : (g == 2) ? wc : wo;
    union { u16 v[8]; uint4 u4; } tmp;
#pragma unroll
    for (int j = 0; j < 8; ++j) {
        int k = ks * 32 + q * 8 + j;
        tmp.v[j] = (k < K) ? load_bf(W, k * 256 + u, fp32) : (u16)0;
    }
    *(uint4*)(wp + ((w * KSTEPS + ks) * 4 + nt) * 512 + lane * 8) = tmp.u4;
    if (ks == 0 && threadIdx.x < 64) {
        int n2 = w * 64 + threadIdx.x;
        int g2 = n2 & 3;
        const void* B = (g2 == 0) ? bbf : (g2 == 1) ? bbi : (g2 == 2) ? bbc : bbo;
        bp[n2] = load_bf(B, n2 >> 2, fp32);
    }
}

// Pack embedding table + w_out/b_out; zero h-exchange buffers + barrier counters
// (re-zeroed every launch/replay so the spin barrier restarts cleanly).
__global__ void pack_misc(const void* emb, const void* w_out, const void* b_out,
                          u16* __restrict__ embp, u16* __restrict__ wob,
                          u16* __restrict__ bob, uint* __restrict__ hzero) {
    __shared__ int sfp;
    if (threadIdx.x == 0) sfp = detect_fp32((const uint*)emb, 256);
    __syncthreads();
    const int fp32 = sfp;
    int gid = blockIdx.x * blockDim.x + threadIdx.x;
    int stride = gridDim.x * blockDim.x;
    for (int i = gid; i < 1000000; i += stride)
        embp[i] = load_bf(emb, i, fp32);
    // zero h1g (2x512KB) + h2g (2x512KB) + barrier counters (16 uints)
    for (int i = gid; i < 524304; i += stride) hzero[i] = 0;
    if (blockIdx.x == 0) {
        __shared__ int sfp2;
        if (threadIdx.x == 0) sfp2 = detect_fp32((const uint*)w_out, 128);
        __syncthreads();
        if (threadIdx.x < 256) wob[threadIdx.x] = load_bf(w_out, threadIdx.x, sfp2);
        if (threadIdx.x == 0) bob[0] = load_bf(b_out, 0, sfp2);
    }
}

// Row-group spin barrier: 16 blocks, device-scope monotonic counter.
// __threadfence() (agent scope) makes prior plain stores LLC-visible (L2 wb)
// before arrival and invalidates stale lines after release.
static __device__ __forceinline__ void group_barrier(uint* cnt, uint target, int tid) {
    __syncthreads();
    if (tid == 0) {
        __threadfence();
        __hip_atomic_fetch_add(cnt, 1u, __ATOMIC_RELAXED, __HIP_MEMORY_SCOPE_AGENT);
        while (__hip_atomic_load(cnt, __ATOMIC_RELAXED, __HIP_MEMORY_SCOPE_AGENT) < target)
            __builtin_amdgcn_s_sleep(1);
        __threadfence();
    }
    __syncthreads();
}

// Persistent-weight LSTM.
// Grid 256 = 16 row-groups (r) x 16 unit-groups (g); block = 1024 thr (16 waves).
// Block (r,g): rows r*64..r*64+63, units g*16..g*16+15 (64 gate-cols).
// Weight slices live in LDS for all 80 steps. h1/h2 double-buffered in global
// (parity = t&1); ONE row-group barrier per step (h1_t RAW before L2-GEMM).
// bid mapping keeps a row-group's 16 blocks on one XCD (bid%8 const).
#define HROWSTRIDE 256
#define HBUFSZ 262144   // 1024*256 u16 per parity

__global__ void __launch_bounds__(1024, 1)
lstm_kernel(const int* __restrict__ tokens, const u16* __restrict__ embp,
            const u16* __restrict__ wp1, const u16* __restrict__ b1p,
            const u16* __restrict__ wp2, const u16* __restrict__ b2p,
            const u16* __restrict__ wob, const u16* __restrict__ bob,
            u16* __restrict__ h1g, u16* __restrict__ h2g,
            uint* __restrict__ bar, float* __restrict__ out) {
    __shared__ __align__(16) u16 w1s[12 * 4 * 512];  // 49152 B  L1 weight slice
    __shared__ __align__(16) u16 w2s[16 * 4 * 512];  // 65536 B  L2 weight slice
    __shared__ __align__(16) u16 xtile[64 * 128];    // 16384 B  x_t (pad zero)
    __shared__ __align__(16) u16 scr[16 * 16 * 20];  // 10240 B  per-wave Z scratch
    // 141312 B total -> 1 block/CU, 256 blocks co-resident

    const int tid = threadIdx.x;
    const int bid = blockIdx.x;
    const int r = (bid & 7) + ((bid >> 7) << 3);  // row-group 0..15 (XCD-affine)
    const int g = (bid >> 3) & 15;                // unit-group 0..15
    const int lane = tid & 63;
    const int wv = tid >> 6;
    const int mt = wv >> 2, nt = wv & 3;          // wave -> (row-tile, col-tile)
    const int c16 = lane & 15, q = lane >> 4;
    const int grow0 = r * 64;

    // gate-phase mapping: thread -> (local row, local unit)
    const int rrg = tid >> 4;      // 0..63
    const int ul = tid & 15;       // 0..15
    const int gu = g * 16 + ul;    // global unit

    // ---- one-time: weights -> LDS, zero xtile pad, x(t=0), biases ----
    {
        const uint4* s1 = (const uint4*)(wp1 + g * (12 * 4 * 512));
        uint4* d1 = (uint4*)w1s;
        for (int i = tid; i < 3072; i += 1024) d1[i] = s1[i];
        const uint4* s2 = (const uint4*)(wp2 + g * (16 * 4 * 512));
        uint4* d2 = (uint4*)w2s;
        for (int i = tid; i < 4096; i += 1024) d2[i] = s2[i];
        uint* xz = (uint*)xtile;
        for (int i = tid; i < 4096; i += 1024) xz[i] = 0;
    }
    __syncthreads();
    for (int item = tid; item < 1600; item += 1024) {
        int rr = item / 25, s = item % 25;
        int tok = tokens[(grow0 + rr) * 80 + 0];
        *(ushort4*)(xtile + rr * 128 + s * 4) = *(const ushort4*)(embp + tok * 100 + s * 4);
    }
    ushort4 bw1 = *(const ushort4*)(b1p + gu * 4);
    ushort4 bw2 = *(const ushort4*)(b2p + gu * 4);
    const float b1f0 = bf2f(bw1.x), b1f1 = bf2f(bw1.y), b1f2 = bf2f(bw1.z), b1f3 = bf2f(bw1.w);
    const float b2f0 = bf2f(bw2.x), b2f1 = bf2f(bw2.y), b2f2 = bf2f(bw2.z), b2f3 = bf2f(bw2.w);
    float c1 = 0.f, c2 = 0.f;
    uint* cnt = bar + r;
    uint phase = 0;
    __syncthreads();

    const int arow = (grow0 + mt * 16 + c16) * HROWSTRIDE + q * 8;

#pragma unroll 1
    for (int t = 0; t < 80; ++t) {
        const int prev = (t & 1) ^ 1;
        const int curp = t & 1;

        // ---------- Layer 1 GEMM: A = [h1_prev | x_t], B = w1s ----------
        {
            const u16* ap = h1g + prev * HBUFSZ + arow;
            uint4 ag[8];
#pragma unroll
            for (int ks = 0; ks < 8; ++ks) ag[ks] = *(const uint4*)(ap + ks * 32);
            const u16* xp = xtile + (mt * 16 + c16) * 128 + q * 8;
            const u16* bp = w1s + nt * 512 + lane * 8;
            f32x4 acc = (f32x4){0.f, 0.f, 0.f, 0.f};
#pragma unroll
            for (int ks = 0; ks < 12; ++ks) {
                bf16x8 a = (ks < 8) ? as_bf16x8(ag[ks])
                                    : as_bf16x8(*(const uint4*)(xp + (ks - 8) * 32));
                bf16x8 b = as_bf16x8(*(const uint4*)(bp + ks * 2048));
                acc = __builtin_amdgcn_mfma_f32_16x16x32_bf16(a, b, acc, 0, 0, 0);
            }
            u16* swv = scr + wv * 320;
#pragma unroll
            for (int j = 0; j < 4; ++j) swv[(q * 4 + j) * 20 + c16] = f2bf(acc[j]);
        }
        __syncthreads();

        // ---------- gates 1 -> h1g[curp]; gather x(t+1) ----------
        {
            const u16* sv = scr + ((rrg >> 4) * 4 + (ul >> 2)) * 320 + (rrg & 15) * 20 + (ul & 3) * 4;
            ushort4 zz = *(const ushort4*)sv;
            float gf = fast_sigmoid(bf2f(zz.x) + b1f0);
            float gi = fast_sigmoid(bf2f(zz.y) + b1f1);
            float gc = fast_tanh(bf2f(zz.z) + b1f2);
            float go = fast_sigmoid(bf2f(zz.w) + b1f3);
            float cn = gf * c1 + gi * gc;
            c1 = cn;
            h1g[curp * HBUFSZ + (grow0 + rrg) * HROWSTRIDE + gu] = f2bf(go * fast_tanh(cn));
        }
        if (t < 79) {
            for (int item = tid; item < 1600; item += 1024) {
                int rr = item / 25, s = item % 25;
                int tok = tokens[(grow0 + rr) * 80 + t + 1];
                *(ushort4*)(xtile + rr * 128 + s * 4) = *(const ushort4*)(embp + tok * 100 + s * 4);
            }
        }

        // ---------- row-group barrier: h1_t visible to all 16 blocks ----------
        ++phase;
        group_barrier(cnt, 16u * phase, tid);

        // ---------- Layer 2 GEMM: A = [h2_prev | h1_cur], B = w2s ----------
        {
            const u16* ap2 = h2g + prev * HBUFSZ + arow;
            const u16* ap1 = h1g + curp * HBUFSZ + arow;
            uint4 ag[16];
#pragma unroll
            for (int ks = 0; ks < 8; ++ks) ag[ks] = *(const uint4*)(ap2 + ks * 32);
#pragma unroll
            for (int ks = 0; ks < 8; ++ks) ag[8 + ks] = *(const uint4*)(ap1 + ks * 32);
            const u16* bp = w2s + nt * 512 + lane * 8;
            f32x4 acc = (f32x4){0.f, 0.f, 0.f, 0.f};
#pragma unroll
            for (int ks = 0; ks < 16; ++ks)
                acc = __builtin_amdgcn_mfma_f32_16x16x32_bf16(
                    as_bf16x8(ag[ks]), as_bf16x8(*(const uint4*)(bp + ks * 2048)), acc, 0, 0, 0);
            u16* swv = scr + wv * 320;
#pragma unroll
            for (int j = 0; j < 4; ++j) swv[(q * 4 + j) * 20 + c16] = f2bf(acc[j]);
        }
        __syncthreads();

        // ---------- gates 2 -> h2g[curp] ----------
        {
            const u16* sv = scr + ((rrg >> 4) * 4 + (ul >> 2)) * 320 + (rrg & 15) * 20 + (ul & 3) * 4;
            ushort4 zz = *(const ushort4*)sv;
            float gf = fast_sigmoid(bf2f(zz.x) + b2f0);
            float gi = fast_sigmoid(bf2f(zz.y) + b2f1);
            float gc = fast_tanh(bf2f(zz.z) + b2f2);
            float go = fast_sigmoid(bf2f(zz.w) + b2f3);
            float cn = gf * c2 + gi * gc;
            c2 = cn;
            h2g[curp * HBUFSZ + (grow0 + rrg) * HROWSTRIDE + gu] = f2bf(go * fast_tanh(cn));
        }
        __syncthreads();  // scratch WAR vs next step's L1 writes
    }

    // final barrier: all h2(t=79) slices visible, then g==0 blocks emit output
    ++phase;
    group_barrier(cnt, 16u * phase, tid);

    if (g == 0) {
        const u16* h2f = h2g + HBUFSZ;  // parity of t=79 is 1
        int rr = tid >> 4, s = tid & 15;
        const u16* hp = h2f + (grow0 + rr) * HROWSTRIDE + s * 16;
        const u16* wq = wob + s * 16;
        float dot = 0.f;
#pragma unroll
        for (int i = 0; i < 16; ++i) dot += bf2f(hp[i]) * bf2f(wq[i]);
        float* ps = (float*)scr;
        ps[rr * 16 + s] = dot;
        __syncthreads();
        if (tid < 64) {
            float ssum = 0.f;
            for (int i = 0; i < 16; ++i) ssum += ps[tid * 16 + i];
            out[grow0 + tid] = fast_sigmoid(ssum + bf2f(bob[0]));
        }
    }
}

extern "C" void kernel_launch(void* const* d_in, const int* in_sizes, int n_in,
                              void* d_out, int out_size, void* d_ws, size_t ws_size,
                              hipStream_t stream) {
    const int* tokens = (const int*)d_in[0];
    const void* emb = d_in[1];
    const void* wf1 = d_in[2];  const void* bf1_ = d_in[3];
    const void* wi1 = d_in[4];  const void* bi1_ = d_in[5];
    const void* wc1 = d_in[6];  const void* bc1_ = d_in[7];
    const void* wo1 = d_in[8];  const void* bo1_ = d_in[9];
    const void* wf2 = d_in[10]; const void* bf2_ = d_in[11];
    const void* wi2 = d_in[12]; const void* bi2_ = d_in[13];
    const void* wc2 = d_in[14]; const void* bc2_ = d_in[15];
    const void* wo2 = d_in[16]; const void* bo2_ = d_in[17];
    const void* w_out = d_in[18];
    const void* b_out = d_in[19];

    u16* wp1 = (u16*)d_ws;                 // 393216
    u16* wp2 = wp1 + 16 * 12 * 4 * 512;    // 524288
    u16* b1p = wp2 + 16 * 16 * 4 * 512;    // 1024
    u16* b2p = b1p + 1024;                 // 1024
    u16* wob = b2p + 1024;                 // 256
    u16* bob = wob + 256;                  // 8 (pad)
    u16* embp = bob + 8;                   // 1,000,000 (16B-aligned)
    u16* h1g = embp + 1000000;             // 2 x 1024 x 256
    u16* h2g = h1g + 2 * 262144;           // 2 x 1024 x 256
    uint* bar = (uint*)(h2g + 2 * 262144); // 16 counters

    pack_w<<<dim3(16 * 12), dim3(256), 0, stream>>>(wf1, wi1, wc1, wo1, bf1_, bi1_, bc1_, bo1_,
                                                    wp1, b1p, 356, 12);
    pack_w<<<dim3(16 * 16), dim3(256), 0, stream>>>(wf2, wi2, wc2, wo2, bf2_, bi2_, bc2_, bo2_,
                                                    wp2, b2p, 512, 16);
    pack_misc<<<dim3(512), dim3(256), 0, stream>>>(emb, w_out, b_out, embp, wob, bob, (uint*)h1g);
    lstm_kernel<<<dim3(256), dim3(1024), 0, stream>>>(tokens, embp, wp1, b1p, wp2, b2p,
                                                      wob, bob, h1g, h2g, bar, (float*)d_out);
}

// Round 5
// 1226.393 us; speedup vs baseline: 3.7749x; 1.4258x over previous
//
#include <hip/hip_runtime.h>

typedef unsigned short u16;
typedef unsigned int uint;

using f32x4 = __attribute__((ext_vector_type(4))) float;
using bf16x8 = __attribute__((ext_vector_type(8))) __bf16;
using u32x4 = __attribute__((ext_vector_type(4))) uint;

static __device__ __forceinline__ bf16x8 as_bf16x8(uint4 u) {
    union { uint4 a; bf16x8 b; } c; c.a = u; return c.b;
}
static __device__ __forceinline__ bf16x8 as_bf16x8v(u32x4 u) {
    union { u32x4 a; bf16x8 b; } c; c.a = u; return c.b;
}
static __device__ __forceinline__ float bf2f(u16 h) {
    union { uint u; float f; } c; c.u = ((uint)h) << 16; return c.f;
}
static __device__ __forceinline__ u16 f2bf(float f) {
    union { float f; uint u; } c; c.f = f;
    uint u = c.u;
    return (u16)((u + 0x7fffu + ((u >> 16) & 1u)) >> 16);
}
static __device__ __forceinline__ float fast_sigmoid(float x) {
    x = fminf(30.f, fmaxf(-30.f, x));
    return __builtin_amdgcn_rcpf(1.0f + __builtin_amdgcn_exp2f(x * -1.44269504f));
}
static __device__ __forceinline__ float fast_tanh(float x) {
    x = fminf(15.f, fmaxf(-15.f, x));
    return 1.0f - 2.0f * __builtin_amdgcn_rcpf(1.0f + __builtin_amdgcn_exp2f(x * 2.88539008f));
}

// L1-bypassing 16B load (sc0): reads the XCD-shared L2 directly, so peer-block
// writes (write-through L1 -> L2) are visible WITHOUT agent-scope fences.
static __device__ __forceinline__ u32x4 load_b128_sc0(const u16* p) {
    u32x4 r;
    asm volatile("global_load_dwordx4 %0, %1, off sc0" : "=v"(r) : "v"(p) : "memory");
    return r;
}
static __device__ __forceinline__ void wait_vm0_fence_sched() {
    asm volatile("s_waitcnt vmcnt(0)" ::: "memory");
    __builtin_amdgcn_sched_barrier(0);   // rule #18: pin MFMA after the wait
}

// dtype detector (fp32 vs bf16 buffers) — deterministic, graph-capture safe.
static __device__ __forceinline__ int detect_fp32(const uint* w, int nwords) {
    int hits = 0;
    for (int i = 0; i < nwords; ++i) { uint e = (w[i] >> 7) & 0xffu; hits += (e >= 0x80u); }
    return hits > (nwords >> 3);
}
static __device__ __forceinline__ u16 load_bf(const void* p, int i, int fp32) {
    return fp32 ? f2bf(((const float*)p)[i]) : ((const u16*)p)[i];
}

// Fragment-ordered weight pack (unchanged layout):
//   wp[((w*KSTEPS + ks)*4 + nt)*512 + lane*8 + j]
__global__ void pack_w(const void* wf, const void* wi, const void* wc, const void* wo,
                       const void* bbf, const void* bbi, const void* bbc, const void* bbo,
                       u16* __restrict__ wp, u16* __restrict__ bp, int K, int KSTEPS) {
    __shared__ int sfp;
    if (threadIdx.x == 0) sfp = detect_fp32((const uint*)wf, 256);
    __syncthreads();
    const int fp32 = sfp;
    int w = blockIdx.x / KSTEPS, ks = blockIdx.x % KSTEPS;
    int nt = threadIdx.x >> 6, lane = threadIdx.x & 63;
    int c16 = lane & 15, q = lane >> 4;
    int n = w * 64 + nt * 16 + c16;
    int u = n >> 2, g = n & 3;
    const void* W = (g == 0) ? wf : (g == 1) ? wi : (g == 2) ? wc : wo;
    union { u16 v[8]; uint4 u4; } tmp;
#pragma unroll
    for (int j = 0; j < 8; ++j) {
        int k = ks * 32 + q * 8 + j;
        tmp.v[j] = (k < K) ? load_bf(W, k * 256 + u, fp32) : (u16)0;
    }
    *(uint4*)(wp + ((w * KSTEPS + ks) * 4 + nt) * 512 + lane * 8) = tmp.u4;
    if (ks == 0 && threadIdx.x < 64) {
        int n2 = w * 64 + threadIdx.x;
        int g2 = n2 & 3;
        const void* B = (g2 == 0) ? bbf : (g2 == 1) ? bbi : (g2 == 2) ? bbc : bbo;
        bp[n2] = load_bf(B, n2 >> 2, fp32);
    }
}

// Pack embedding table + w_out/b_out; zero h-exchange buffers + barrier counters
// (re-zeroed every launch/replay so the spin barrier restarts cleanly).
__global__ void pack_misc(const void* emb, const void* w_out, const void* b_out,
                          u16* __restrict__ embp, u16* __restrict__ wob,
                          u16* __restrict__ bob, uint* __restrict__ hzero) {
    __shared__ int sfp;
    if (threadIdx.x == 0) sfp = detect_fp32((const uint*)emb, 256);
    __syncthreads();
    const int fp32 = sfp;
    int gid = blockIdx.x * blockDim.x + threadIdx.x;
    int stride = gridDim.x * blockDim.x;
    for (int i = gid; i < 1000000; i += stride)
        embp[i] = load_bf(emb, i, fp32);
    // zero h1g (2x512KB) + h2g (2x512KB) + barrier counters (16 uints)
    for (int i = gid; i < 524304; i += stride) hzero[i] = 0;
    if (blockIdx.x == 0) {
        __shared__ int sfp2;
        if (threadIdx.x == 0) sfp2 = detect_fp32((const uint*)w_out, 128);
        __syncthreads();
        if (threadIdx.x < 256) wob[threadIdx.x] = load_bf(w_out, threadIdx.x, sfp2);
        if (threadIdx.x == 0) bob[0] = load_bf(b_out, 0, sfp2);
    }
}

// Row-group spin barrier WITHOUT agent fences (the round-4 L2-killer).
// Correctness protocol (intra-XCD): writer drains stores to the shared L2
// (write-through L1) via vmcnt(0) before arrival; readers use sc0 loads that
// bypass their CU-local L1. The counter itself is a device-scope atomic
// (coherent chip-wide regardless of block->XCD placement).
static __device__ __forceinline__ void group_barrier(uint* cnt, uint target, int tid) {
    asm volatile("s_waitcnt vmcnt(0)" ::: "memory");
    __syncthreads();
    if (tid == 0) {
        __hip_atomic_fetch_add(cnt, 1u, __ATOMIC_RELAXED, __HIP_MEMORY_SCOPE_AGENT);
        while (__hip_atomic_load(cnt, __ATOMIC_RELAXED, __HIP_MEMORY_SCOPE_AGENT) < target)
            __builtin_amdgcn_s_sleep(1);
    }
    __syncthreads();
}

// Persistent-weight LSTM.
// Grid 256 = 16 row-groups (r) x 16 unit-groups (g); block = 1024 thr (16 waves).
// Weight slices live in LDS for all 80 steps. h1/h2 double-buffered in global
// (parity = t&1); ONE row-group barrier per step. bid mapping keeps a
// row-group's 16 blocks on one XCD (bid%8 const) -> h exchange stays in L2.
#define HROWSTRIDE 256
#define HBUFSZ 262144   // 1024*256 u16 per parity

__global__ void __launch_bounds__(1024, 1)
lstm_kernel(const int* __restrict__ tokens, const u16* __restrict__ embp,
            const u16* __restrict__ wp1, const u16* __restrict__ b1p,
            const u16* __restrict__ wp2, const u16* __restrict__ b2p,
            const u16* __restrict__ wob, const u16* __restrict__ bob,
            u16* __restrict__ h1g, u16* __restrict__ h2g,
            uint* __restrict__ bar, float* __restrict__ out) {
    __shared__ __align__(16) u16 w1s[12 * 4 * 512];  // 49152 B  L1 weight slice
    __shared__ __align__(16) u16 w2s[16 * 4 * 512];  // 65536 B  L2 weight slice
    __shared__ __align__(16) u16 xtile[64 * 128];    // 16384 B  x_t (pad zero)
    __shared__ __align__(16) u16 scr[16 * 16 * 20];  // 10240 B  per-wave Z scratch
    // 141312 B total -> 1 block/CU, 256 blocks co-resident

    const int tid = threadIdx.x;
    const int bid = blockIdx.x;
    const int r = (bid & 7) + ((bid >> 7) << 3);  // row-group 0..15 (XCD-affine)
    const int g = (bid >> 3) & 15;                // unit-group 0..15
    const int lane = tid & 63;
    const int wv = tid >> 6;
    const int mt = wv >> 2, nt = wv & 3;          // wave -> (row-tile, col-tile)
    const int c16 = lane & 15, q = lane >> 4;
    const int grow0 = r * 64;

    const int rrg = tid >> 4;      // gate phase: local row 0..63
    const int ul = tid & 15;       // local unit
    const int gu = g * 16 + ul;    // global unit

    // ---- one-time: weights -> LDS, zero xtile pad, x(t=0), biases ----
    {
        const uint4* s1 = (const uint4*)(wp1 + g * (12 * 4 * 512));
        uint4* d1 = (uint4*)w1s;
        for (int i = tid; i < 3072; i += 1024) d1[i] = s1[i];
        const uint4* s2 = (const uint4*)(wp2 + g * (16 * 4 * 512));
        uint4* d2 = (uint4*)w2s;
        for (int i = tid; i < 4096; i += 1024) d2[i] = s2[i];
        uint* xz = (uint*)xtile;
        for (int i = tid; i < 4096; i += 1024) xz[i] = 0;
    }
    __syncthreads();
    for (int item = tid; item < 1600; item += 1024) {
        int rr = item / 25, s = item % 25;
        int tok = tokens[(grow0 + rr) * 80 + 0];
        *(ushort4*)(xtile + rr * 128 + s * 4) = *(const ushort4*)(embp + tok * 100 + s * 4);
    }
    ushort4 bw1 = *(const ushort4*)(b1p + gu * 4);
    ushort4 bw2 = *(const ushort4*)(b2p + gu * 4);
    const float b1f0 = bf2f(bw1.x), b1f1 = bf2f(bw1.y), b1f2 = bf2f(bw1.z), b1f3 = bf2f(bw1.w);
    const float b2f0 = bf2f(bw2.x), b2f1 = bf2f(bw2.y), b2f2 = bf2f(bw2.z), b2f3 = bf2f(bw2.w);
    float c1 = 0.f, c2 = 0.f;
    uint* cnt = bar + r;
    uint phase = 0;
    __syncthreads();

    const int arow = (grow0 + mt * 16 + c16) * HROWSTRIDE + q * 8;

#pragma unroll 1
    for (int t = 0; t < 80; ++t) {
        const int prev = (t & 1) ^ 1;
        const int curp = t & 1;

        // ---------- Layer 1 GEMM: A = [h1_prev | x_t], B = w1s ----------
        {
            const u16* ap = h1g + prev * HBUFSZ + arow;
            u32x4 ag[8];
#pragma unroll
            for (int ks = 0; ks < 8; ++ks) ag[ks] = load_b128_sc0(ap + ks * 32);
            wait_vm0_fence_sched();
            const u16* xp = xtile + (mt * 16 + c16) * 128 + q * 8;
            const u16* bp = w1s + nt * 512 + lane * 8;
            f32x4 acc = (f32x4){0.f, 0.f, 0.f, 0.f};
#pragma unroll
            for (int ks = 0; ks < 12; ++ks) {
                bf16x8 a = (ks < 8) ? as_bf16x8v(ag[ks])
                                    : as_bf16x8(*(const uint4*)(xp + (ks - 8) * 32));
                bf16x8 b = as_bf16x8(*(const uint4*)(bp + ks * 2048));
                acc = __builtin_amdgcn_mfma_f32_16x16x32_bf16(a, b, acc, 0, 0, 0);
            }
            u16* swv = scr + wv * 320;
#pragma unroll
            for (int j = 0; j < 4; ++j) swv[(q * 4 + j) * 20 + c16] = f2bf(acc[j]);
        }
        __syncthreads();

        // ---------- gates 1 -> h1g[curp]; gather x(t+1) ----------
        {
            const u16* sv = scr + ((rrg >> 4) * 4 + (ul >> 2)) * 320 + (rrg & 15) * 20 + (ul & 3) * 4;
            ushort4 zz = *(const ushort4*)sv;
            float gf = fast_sigmoid(bf2f(zz.x) + b1f0);
            float gi = fast_sigmoid(bf2f(zz.y) + b1f1);
            float gc = fast_tanh(bf2f(zz.z) + b1f2);
            float go = fast_sigmoid(bf2f(zz.w) + b1f3);
            float cn = gf * c1 + gi * gc;
            c1 = cn;
            h1g[curp * HBUFSZ + (grow0 + rrg) * HROWSTRIDE + gu] = f2bf(go * fast_tanh(cn));
        }
        if (t < 79) {
            for (int item = tid; item < 1600; item += 1024) {
                int rr = item / 25, s = item % 25;
                int tok = tokens[(grow0 + rr) * 80 + t + 1];
                *(ushort4*)(xtile + rr * 128 + s * 4) = *(const ushort4*)(embp + tok * 100 + s * 4);
            }
        }

        // ---------- row-group barrier: h1_t drained to L2, visible to peers ----------
        ++phase;
        group_barrier(cnt, 16u * phase, tid);

        // ---------- Layer 2 GEMM: A = [h2_prev | h1_cur], B = w2s ----------
        {
            const u16* ap2 = h2g + prev * HBUFSZ + arow;
            const u16* ap1 = h1g + curp * HBUFSZ + arow;
            u32x4 ag[16];
#pragma unroll
            for (int ks = 0; ks < 8; ++ks) ag[ks] = load_b128_sc0(ap2 + ks * 32);
#pragma unroll
            for (int ks = 0; ks < 8; ++ks) ag[8 + ks] = load_b128_sc0(ap1 + ks * 32);
            wait_vm0_fence_sched();
            const u16* bp = w2s + nt * 512 + lane * 8;
            f32x4 acc = (f32x4){0.f, 0.f, 0.f, 0.f};
#pragma unroll
            for (int ks = 0; ks < 16; ++ks)
                acc = __builtin_amdgcn_mfma_f32_16x16x32_bf16(
                    as_bf16x8v(ag[ks]), as_bf16x8(*(const uint4*)(bp + ks * 2048)), acc, 0, 0, 0);
            u16* swv = scr + wv * 320;
#pragma unroll
            for (int j = 0; j < 4; ++j) swv[(q * 4 + j) * 20 + c16] = f2bf(acc[j]);
        }
        __syncthreads();

        // ---------- gates 2 -> h2g[curp] ----------
        {
            const u16* sv = scr + ((rrg >> 4) * 4 + (ul >> 2)) * 320 + (rrg & 15) * 20 + (ul & 3) * 4;
            ushort4 zz = *(const ushort4*)sv;
            float gf = fast_sigmoid(bf2f(zz.x) + b2f0);
            float gi = fast_sigmoid(bf2f(zz.y) + b2f1);
            float gc = fast_tanh(bf2f(zz.z) + b2f2);
            float go = fast_sigmoid(bf2f(zz.w) + b2f3);
            float cn = gf * c2 + gi * gc;
            c2 = cn;
            h2g[curp * HBUFSZ + (grow0 + rrg) * HROWSTRIDE + gu] = f2bf(go * fast_tanh(cn));
        }
        __syncthreads();  // scratch WAR vs next step's L1 writes
    }

    // final barrier: all h2(t=79) slices drained, then g==0 blocks emit output
    ++phase;
    group_barrier(cnt, 16u * phase, tid);

    if (g == 0) {
        const u16* h2f = h2g + HBUFSZ;  // parity of t=79 is 1
        int rr = tid >> 4, s = tid & 15;
        const u16* hp = h2f + (grow0 + rr) * HROWSTRIDE + s * 16;
        u32x4 hv0 = load_b128_sc0(hp);
        u32x4 hv1 = load_b128_sc0(hp + 8);
        wait_vm0_fence_sched();
        const u16* wq = wob + s * 16;
        union { u32x4 v[2]; u16 h[16]; } hu; hu.v[0] = hv0; hu.v[1] = hv1;
        float dot = 0.f;
#pragma unroll
        for (int i = 0; i < 16; ++i) dot += bf2f(hu.h[i]) * bf2f(wq[i]);
        float* ps = (float*)scr;
        ps[rr * 16 + s] = dot;
        __syncthreads();
        if (tid < 64) {
            float ssum = 0.f;
            for (int i = 0; i < 16; ++i) ssum += ps[tid * 16 + i];
            out[grow0 + tid] = fast_sigmoid(ssum + bf2f(bob[0]));
        }
    }
}

extern "C" void kernel_launch(void* const* d_in, const int* in_sizes, int n_in,
                              void* d_out, int out_size, void* d_ws, size_t ws_size,
                              hipStream_t stream) {
    const int* tokens = (const int*)d_in[0];
    const void* emb = d_in[1];
    const void* wf1 = d_in[2];  const void* bf1_ = d_in[3];
    const void* wi1 = d_in[4];  const void* bi1_ = d_in[5];
    const void* wc1 = d_in[6];  const void* bc1_ = d_in[7];
    const void* wo1 = d_in[8];  const void* bo1_ = d_in[9];
    const void* wf2 = d_in[10]; const void* bf2_ = d_in[11];
    const void* wi2 = d_in[12]; const void* bi2_ = d_in[13];
    const void* wc2 = d_in[14]; const void* bc2_ = d_in[15];
    const void* wo2 = d_in[16]; const void* bo2_ = d_in[17];
    const void* w_out = d_in[18];
    const void* b_out = d_in[19];

    u16* wp1 = (u16*)d_ws;                 // 393216
    u16* wp2 = wp1 + 16 * 12 * 4 * 512;    // 524288
    u16* b1p = wp2 + 16 * 16 * 4 * 512;    // 1024
    u16* b2p = b1p + 1024;                 // 1024
    u16* wob = b2p + 1024;                 // 256
    u16* bob = wob + 256;                  // 8 (pad)
    u16* embp = bob + 8;                   // 1,000,000 (16B-aligned)
    u16* h1g = embp + 1000000;             // 2 x 1024 x 256
    u16* h2g = h1g + 2 * 262144;           // 2 x 1024 x 256
    uint* bar = (uint*)(h2g + 2 * 262144); // 16 counters

    pack_w<<<dim3(16 * 12), dim3(256), 0, stream>>>(wf1, wi1, wc1, wo1, bf1_, bi1_, bc1_, bo1_,
                                                    wp1, b1p, 356, 12);
    pack_w<<<dim3(16 * 16), dim3(256), 0, stream>>>(wf2, wi2, wc2, wo2, bf2_, bi2_, bc2_, bo2_,
                                                    wp2, b2p, 512, 16);
    pack_misc<<<dim3(512), dim3(256), 0, stream>>>(emb, w_out, b_out, embp, wob, bob, (uint*)h1g);
    lstm_kernel<<<dim3(256), dim3(1024), 0, stream>>>(tokens, embp, wp1, b1p, wp2, b2p,
                                                      wob, bob, h1g, h2g, bar, (float*)d_out);
}